// Round 2
// baseline (222.237 us; speedup 1.0000x reference)
//
#include <hip/hip_runtime.h>

// Problem constants
#define NB   8192
#define ND   256
#define NH1  50
#define NH2  32
#define NH3  18
#define RPB  16              // rows per block
#define NBLK (NB / RPB)      // 512 blocks
#define W1TS 260             // W1T LDS row stride (dwords): %4==0 for b128 align,
                             // 16 lanes * 4 dwords = 64 consecutive dwords -> 2-way (free)

// ws float layout: [0..17] ysum, [18..35] colsum(W_user), [36] sum(log_denom)

__device__ __forceinline__ float sigmoidf_fast(float v) {
    return 1.0f / (1.0f + __expf(-v));
}

__global__ __launch_bounds__(256) void fused_main(
    const float* __restrict__ x, const float* __restrict__ y,
    const float* __restrict__ W1, const float* __restrict__ b1,
    const float* __restrict__ W2, const float* __restrict__ b2,
    const float* __restrict__ W3, const float* __restrict__ b3,
    float* __restrict__ out, float* __restrict__ ws)
{
    __shared__ float w1t[NH1 * W1TS];      // W1 transposed [j][k], 52000 B
    __shared__ float w2l[NH1 * NH2];       // W2 [j][c], 6400 B
    __shared__ float w3l[NH2 * NH3];       // W3 [j][c], 2304 B
    __shared__ float h2l[RPB][NH2 + 2];    // stride 34 (even, de-conflicted), 2176 B
    __shared__ float wul[RPB][NH3 + 1];    // stride 19, 1216 B
    // total ~64 KB, 2 blocks/CU

    const int t    = threadIdx.x;
    const int row  = t >> 4;          // 0..15 local row
    const int ksl  = t & 15;          // k-slice within row
    const int grow = blockIdx.x * RPB + row;

    // ---- issue x loads first (independent of LDS staging; stays in flight) ----
    const float* xrow = x + (size_t)grow * ND + ksl * 4;
    const float4 xv0 = *reinterpret_cast<const float4*>(xrow + 0);
    const float4 xv1 = *reinterpret_cast<const float4*>(xrow + 64);
    const float4 xv2 = *reinterpret_cast<const float4*>(xrow + 128);
    const float4 xv3 = *reinterpret_cast<const float4*>(xrow + 192);

    // ---- stage weights into LDS (W1 transposed) ----
    for (int e = t; e < ND * NH1; e += 256) {     // 50 iters, coalesced reads
        int k = e / NH1;
        int j = e - k * NH1;
        w1t[j * W1TS + k] = W1[e];
    }
    for (int e = t; e < NH1 * NH2; e += 256) w2l[e] = W2[e];
    for (int e = t; e < NH2 * NH3; e += 256) w3l[e] = W3[e];
    __syncthreads();

    // ---- layer 1: partial over this lane's 16 k values, then 16-lane butterfly ----
    float h1[NH1];
#pragma unroll
    for (int j = 0; j < NH1; ++j) {
        const float* wj = &w1t[j * W1TS + ksl * 4];
        const float4 w0 = *reinterpret_cast<const float4*>(wj + 0);
        const float4 w1v = *reinterpret_cast<const float4*>(wj + 64);
        const float4 w2v = *reinterpret_cast<const float4*>(wj + 128);
        const float4 w3v = *reinterpret_cast<const float4*>(wj + 192);
        float a;
        a = xv0.x * w0.x;
        a = fmaf(xv0.y, w0.y, a);
        a = fmaf(xv0.z, w0.z, a);
        a = fmaf(xv0.w, w0.w, a);
        a = fmaf(xv1.x, w1v.x, a);
        a = fmaf(xv1.y, w1v.y, a);
        a = fmaf(xv1.z, w1v.z, a);
        a = fmaf(xv1.w, w1v.w, a);
        a = fmaf(xv2.x, w2v.x, a);
        a = fmaf(xv2.y, w2v.y, a);
        a = fmaf(xv2.z, w2v.z, a);
        a = fmaf(xv2.w, w2v.w, a);
        a = fmaf(xv3.x, w3v.x, a);
        a = fmaf(xv3.y, w3v.y, a);
        a = fmaf(xv3.z, w3v.z, a);
        a = fmaf(xv3.w, w3v.w, a);
        h1[j] = a;
    }
#pragma unroll
    for (int j = 0; j < NH1; ++j) {
        float v = h1[j];
        v += __shfl_xor(v, 1, 64);
        v += __shfl_xor(v, 2, 64);
        v += __shfl_xor(v, 4, 64);
        v += __shfl_xor(v, 8, 64);     // all 16 lanes now hold the full k-sum
        h1[j] = sigmoidf_fast(v + b1[j]);
    }

    // ---- layer 2: each lane computes 2 of 32 cols for its row ----
    {
        const float2 bb = *reinterpret_cast<const float2*>(b2 + 2 * ksl);
        float h2a = bb.x, h2b = bb.y;
#pragma unroll
        for (int j = 0; j < NH1; ++j) {
            const float2 w = *reinterpret_cast<const float2*>(&w2l[j * NH2 + 2 * ksl]);
            h2a = fmaf(h1[j], w.x, h2a);
            h2b = fmaf(h1[j], w.y, h2b);
        }
        h2a = sigmoidf_fast(h2a);
        h2b = sigmoidf_fast(h2b);
        *reinterpret_cast<float2*>(&h2l[row][2 * ksl]) = make_float2(h2a, h2b);
    }
    __syncthreads();

    // ---- layer 3: lane computes col ksl (and 16+ksl for ksl<2) ----
    {
        float a0 = b3[ksl];
        float a1 = (ksl < 2) ? b3[16 + ksl] : 0.0f;
#pragma unroll
        for (int j = 0; j < NH2; ++j) {
            const float h = h2l[row][j];              // broadcast within 16-group
            a0 = fmaf(h, w3l[j * NH3 + ksl], a0);
            if (ksl < 2) a1 = fmaf(h, w3l[j * NH3 + 16 + ksl], a1);
        }
        wul[row][ksl] = a0;
        out[(size_t)grow * NH3 + ksl] = a0;
        if (ksl < 2) {
            wul[row][16 + ksl] = a1;
            out[(size_t)grow * NH3 + 16 + ksl] = a1;
        }
    }
    __syncthreads();

    // ---- epilogue on wave 0: factorized LSE + block reductions + atomics ----
    if (t < 64) {
        const bool act = t < RPB;
        float wv[NH3], yv[NH3];
        const float* yrow = y + (size_t)(blockIdx.x * RPB + t) * NH3;
#pragma unroll
        for (int c = 0; c < NH3; ++c) {
            wv[c] = act ? wul[t][c] : 0.0f;
            yv[c] = act ? yrow[c]   : 0.0f;
        }

        // factorized logsumexp over cartesian one-hot cases: groups [0,2)[2,6)[6,10)[10,18)
        float ld = 0.0f;
        if (act) {
            float m = fmaxf(wv[0], wv[1]);
            ld += m + __logf(__expf(wv[0] - m) + __expf(wv[1] - m));
            m = fmaxf(fmaxf(wv[2], wv[3]), fmaxf(wv[4], wv[5]));
            ld += m + __logf(__expf(wv[2] - m) + __expf(wv[3] - m) +
                             __expf(wv[4] - m) + __expf(wv[5] - m));
            m = fmaxf(fmaxf(wv[6], wv[7]), fmaxf(wv[8], wv[9]));
            ld += m + __logf(__expf(wv[6] - m) + __expf(wv[7] - m) +
                             __expf(wv[8] - m) + __expf(wv[9] - m));
            m = wv[10];
#pragma unroll
            for (int i = 11; i < NH3; ++i) m = fmaxf(m, wv[i]);
            float s = 0.0f;
#pragma unroll
            for (int i = 10; i < NH3; ++i) s += __expf(wv[i] - m);
            ld += m + __logf(s);
        }

        // reduce within the 16-lane group containing lanes 0..15
        ld += __shfl_xor(ld, 1, 64);
        ld += __shfl_xor(ld, 2, 64);
        ld += __shfl_xor(ld, 4, 64);
        ld += __shfl_xor(ld, 8, 64);
#pragma unroll
        for (int c = 0; c < NH3; ++c) {
            float v = wv[c];
            v += __shfl_xor(v, 1, 64);
            v += __shfl_xor(v, 2, 64);
            v += __shfl_xor(v, 4, 64);
            v += __shfl_xor(v, 8, 64);
            wv[c] = v;
            float u = yv[c];
            u += __shfl_xor(u, 1, 64);
            u += __shfl_xor(u, 2, 64);
            u += __shfl_xor(u, 4, 64);
            u += __shfl_xor(u, 8, 64);
            yv[c] = u;
        }
        if (t == 0) {
#pragma unroll
            for (int c = 0; c < NH3; ++c) {
                atomicAdd(ws + c, yv[c]);            // ysum
                atomicAdd(ws + NH3 + c, wv[c]);      // colsum(W_user)
            }
            atomicAdd(ws + 36, ld);                  // sum(log_denom)
        }
    }
}

__global__ void finalize_loss(const float* __restrict__ ws, float* __restrict__ out) {
    if (threadIdx.x == 0) {
        double s = 0.0;
#pragma unroll
        for (int c = 0; c < NH3; ++c)
            s += (double)ws[NH3 + c] * (double)ws[c];   // colsum . ysum == sum(S)
        out[(size_t)NB * NH3] = (float)(-(s - (double)ws[36]));
    }
}

extern "C" void kernel_launch(void* const* d_in, const int* in_sizes, int n_in,
                              void* d_out, int out_size, void* d_ws, size_t ws_size,
                              hipStream_t stream) {
    const float* x  = (const float*)d_in[0];
    const float* y  = (const float*)d_in[1];
    const float* W1 = (const float*)d_in[2];
    const float* b1 = (const float*)d_in[3];
    const float* W2 = (const float*)d_in[4];
    const float* b2 = (const float*)d_in[5];
    const float* W3 = (const float*)d_in[6];
    const float* b3 = (const float*)d_in[7];
    // d_in[8] (cases) folded into the factorized logsumexp.
    float* out = (float*)d_out;
    float* ws  = (float*)d_ws;

    hipMemsetAsync(ws, 0, 37 * sizeof(float), stream);
    fused_main<<<dim3(NBLK), dim3(256), 0, stream>>>(x, y, W1, b1, W2, b2, W3, b3, out, ws);
    finalize_loss<<<dim3(1), dim3(64), 0, stream>>>(ws, out);
}

// Round 4
// 103.295 us; speedup vs baseline: 2.1515x; 2.1515x over previous
//
#include <hip/hip_runtime.h>

// Problem constants
#define NB   8192
#define ND   256
#define NH1  50
#define NH2  32
#define NH3  18
#define RPB  16              // rows per block
#define NBLK (NB / RPB)      // 512 blocks
#define W1TS 260             // W1T LDS row stride (dwords): %4==0 for b128 align
#define WSS  40              // per-block ws slot stride (floats)

// ws layout: ws[b*WSS + c], c: [0..17] ysum part, [18..35] colsum(W_user) part,
//            [36] sum(log_denom) part. No atomics, no zero-init needed.

__device__ __forceinline__ float sigmoidf_fast(float v) {
    return 1.0f / (1.0f + __expf(-v));
}

__global__ __launch_bounds__(256) void fused_main(
    const float* __restrict__ x, const float* __restrict__ y,
    const float* __restrict__ W1, const float* __restrict__ b1,
    const float* __restrict__ W2, const float* __restrict__ b2,
    const float* __restrict__ W3, const float* __restrict__ b3,
    float* __restrict__ out, float* __restrict__ ws)
{
    __shared__ float w1t[NH1 * W1TS];      // W1 transposed [j][k], 52000 B
    __shared__ float w2l[NH1 * NH2];       // W2 [j][c], 6400 B
    __shared__ float w3l[NH2 * NH3];       // W3 [j][c], 2304 B
    __shared__ float h2l[RPB][NH2 + 2];    // stride 34, 2176 B
    __shared__ float wul[RPB][NH3 + 1];    // stride 19, 1216 B

    const int t    = threadIdx.x;
    const int row  = t >> 4;          // 0..15 local row
    const int ksl  = t & 15;          // k-slice within row
    const int grow = blockIdx.x * RPB + row;

    // ---- issue x loads first (independent of LDS staging; stays in flight) ----
    const float* xrow = x + (size_t)grow * ND + ksl * 4;
    const float4 xv0 = *reinterpret_cast<const float4*>(xrow + 0);
    const float4 xv1 = *reinterpret_cast<const float4*>(xrow + 64);
    const float4 xv2 = *reinterpret_cast<const float4*>(xrow + 128);
    const float4 xv3 = *reinterpret_cast<const float4*>(xrow + 192);

    // ---- stage weights into LDS (W1 transposed) ----
    for (int e = t; e < ND * NH1; e += 256) {     // 50 iters, coalesced reads
        int k = e / NH1;
        int j = e - k * NH1;
        w1t[j * W1TS + k] = W1[e];
    }
    for (int e = t; e < NH1 * NH2; e += 256) w2l[e] = W2[e];
    for (int e = t; e < NH2 * NH3; e += 256) w3l[e] = W3[e];
    __syncthreads();

    // ---- layer 1: partial over this lane's 16 k values, then 16-lane butterfly ----
    float h1[NH1];
#pragma unroll
    for (int j = 0; j < NH1; ++j) {
        const float* wj = &w1t[j * W1TS + ksl * 4];
        const float4 w0 = *reinterpret_cast<const float4*>(wj + 0);
        const float4 w1v = *reinterpret_cast<const float4*>(wj + 64);
        const float4 w2v = *reinterpret_cast<const float4*>(wj + 128);
        const float4 w3v = *reinterpret_cast<const float4*>(wj + 192);
        float a;
        a = xv0.x * w0.x;
        a = fmaf(xv0.y, w0.y, a);
        a = fmaf(xv0.z, w0.z, a);
        a = fmaf(xv0.w, w0.w, a);
        a = fmaf(xv1.x, w1v.x, a);
        a = fmaf(xv1.y, w1v.y, a);
        a = fmaf(xv1.z, w1v.z, a);
        a = fmaf(xv1.w, w1v.w, a);
        a = fmaf(xv2.x, w2v.x, a);
        a = fmaf(xv2.y, w2v.y, a);
        a = fmaf(xv2.z, w2v.z, a);
        a = fmaf(xv2.w, w2v.w, a);
        a = fmaf(xv3.x, w3v.x, a);
        a = fmaf(xv3.y, w3v.y, a);
        a = fmaf(xv3.z, w3v.z, a);
        a = fmaf(xv3.w, w3v.w, a);
        h1[j] = a;
    }
#pragma unroll
    for (int j = 0; j < NH1; ++j) {
        float v = h1[j];
        v += __shfl_xor(v, 1, 64);
        v += __shfl_xor(v, 2, 64);
        v += __shfl_xor(v, 4, 64);
        v += __shfl_xor(v, 8, 64);     // all 16 lanes now hold the full k-sum
        h1[j] = sigmoidf_fast(v + b1[j]);
    }

    // ---- layer 2: each lane computes 2 of 32 cols for its row ----
    {
        const float2 bb = *reinterpret_cast<const float2*>(b2 + 2 * ksl);
        float h2a = bb.x, h2b = bb.y;
#pragma unroll
        for (int j = 0; j < NH1; ++j) {
            const float2 w = *reinterpret_cast<const float2*>(&w2l[j * NH2 + 2 * ksl]);
            h2a = fmaf(h1[j], w.x, h2a);
            h2b = fmaf(h1[j], w.y, h2b);
        }
        h2a = sigmoidf_fast(h2a);
        h2b = sigmoidf_fast(h2b);
        *reinterpret_cast<float2*>(&h2l[row][2 * ksl]) = make_float2(h2a, h2b);
    }
    __syncthreads();

    // ---- layer 3: lane computes col ksl (and 16+ksl for ksl<2) ----
    {
        float a0 = b3[ksl];
        float a1 = (ksl < 2) ? b3[16 + ksl] : 0.0f;
#pragma unroll
        for (int j = 0; j < NH2; ++j) {
            const float h = h2l[row][j];              // broadcast within 16-group
            a0 = fmaf(h, w3l[j * NH3 + ksl], a0);
            if (ksl < 2) a1 = fmaf(h, w3l[j * NH3 + 16 + ksl], a1);
        }
        wul[row][ksl] = a0;
        out[(size_t)grow * NH3 + ksl] = a0;
        if (ksl < 2) {
            wul[row][16 + ksl] = a1;
            out[(size_t)grow * NH3 + 16 + ksl] = a1;
        }
    }
    __syncthreads();

    // ---- epilogue on wave 0: factorized LSE + block reductions, NO global atomics ----
    if (t < 64) {
        const bool act = t < RPB;
        float wv[NH3], yv[NH3];
        float ld = 0.0f;
        if (act) {
            const float* yrow = y + (size_t)(blockIdx.x * RPB + t) * NH3;
#pragma unroll
            for (int c = 0; c < NH3; ++c) {
                wv[c] = wul[t][c];
                yv[c] = yrow[c];
            }
            // factorized logsumexp over cartesian one-hot cases:
            // groups [0,2) [2,6) [6,10) [10,18)
            float m = fmaxf(wv[0], wv[1]);
            ld += m + __logf(__expf(wv[0] - m) + __expf(wv[1] - m));
            m = fmaxf(fmaxf(wv[2], wv[3]), fmaxf(wv[4], wv[5]));
            ld += m + __logf(__expf(wv[2] - m) + __expf(wv[3] - m) +
                             __expf(wv[4] - m) + __expf(wv[5] - m));
            m = fmaxf(fmaxf(wv[6], wv[7]), fmaxf(wv[8], wv[9]));
            ld += m + __logf(__expf(wv[6] - m) + __expf(wv[7] - m) +
                             __expf(wv[8] - m) + __expf(wv[9] - m));
            m = wv[10];
#pragma unroll
            for (int i = 11; i < NH3; ++i) m = fmaxf(m, wv[i]);
            float s = 0.0f;
#pragma unroll
            for (int i = 10; i < NH3; ++i) s += __expf(wv[i] - m);
            ld += m + __logf(s);
        } else {
#pragma unroll
            for (int c = 0; c < NH3; ++c) { wv[c] = 0.0f; yv[c] = 0.0f; }
        }

        // 16-lane butterflies; group 0 (lanes 0..15) ends with the block totals
        ld += __shfl_xor(ld, 1, 64);
        ld += __shfl_xor(ld, 2, 64);
        ld += __shfl_xor(ld, 4, 64);
        ld += __shfl_xor(ld, 8, 64);
#pragma unroll
        for (int c = 0; c < NH3; ++c) {
            float v = wv[c];
            v += __shfl_xor(v, 1, 64);
            v += __shfl_xor(v, 2, 64);
            v += __shfl_xor(v, 4, 64);
            v += __shfl_xor(v, 8, 64);
            wv[c] = v;
            float u = yv[c];
            u += __shfl_xor(u, 1, 64);
            u += __shfl_xor(u, 2, 64);
            u += __shfl_xor(u, 4, 64);
            u += __shfl_xor(u, 8, 64);
            yv[c] = u;
        }
        if (t == 0) {
            float* slot = ws + (size_t)blockIdx.x * WSS;
#pragma unroll
            for (int c = 0; c < NH3; ++c) {
                slot[c]       = yv[c];       // ysum partial
                slot[NH3 + c] = wv[c];       // colsum(W_user) partial
            }
            slot[36] = ld;                   // log_denom partial
        }
    }
}

__global__ __launch_bounds__(256) void finalize_loss(
    const float* __restrict__ ws, float* __restrict__ out)
{
    __shared__ double part[4][37];
    const int t = threadIdx.x;
    const int w = t >> 6, l = t & 63;
    if (l < 37) {
        double a = 0.0;
        for (int b = w * (NBLK / 4); b < (w + 1) * (NBLK / 4); ++b)
            a += (double)ws[(size_t)b * WSS + l];   // lanes 0..36 coalesced
        part[w][l] = a;
    }
    __syncthreads();
    if (t == 0) {
        double tot[37];
#pragma unroll
        for (int c = 0; c < 37; ++c)
            tot[c] = part[0][c] + part[1][c] + part[2][c] + part[3][c];
        double s = 0.0;
#pragma unroll
        for (int c = 0; c < NH3; ++c)
            s += tot[NH3 + c] * tot[c];             // colsum(W_user) . ysum == sum(S)
        out[(size_t)NB * NH3] = (float)(-(s - tot[36]));
    }
}

extern "C" void kernel_launch(void* const* d_in, const int* in_sizes, int n_in,
                              void* d_out, int out_size, void* d_ws, size_t ws_size,
                              hipStream_t stream) {
    const float* x  = (const float*)d_in[0];
    const float* y  = (const float*)d_in[1];
    const float* W1 = (const float*)d_in[2];
    const float* b1 = (const float*)d_in[3];
    const float* W2 = (const float*)d_in[4];
    const float* b2 = (const float*)d_in[5];
    const float* W3 = (const float*)d_in[6];
    const float* b3 = (const float*)d_in[7];
    // d_in[8] (cases) folded into the factorized logsumexp.
    float* out = (float*)d_out;
    float* ws  = (float*)d_ws;

    // No memset needed: every ws slot read by finalize_loss is written
    // unconditionally by fused_main.
    fused_main<<<dim3(NBLK), dim3(256), 0, stream>>>(x, y, W1, b1, W2, b2, W3, b3, out, ws);
    finalize_loss<<<dim3(1), dim3(256), 0, stream>>>(ws, out);
}